// Round 6
// baseline (32.597 us; speedup 1.0000x reference)
//
#include <hip/hip_runtime.h>
#include <stdint.h>

// DeLaN forward, D=2, H1=64 — 32x32x16 MFMA, 32 samples/wave, LDS only for
// W1a A-fragments (16 KB); all other constants via L1-broadcast global loads.
// Numerics = R3/R5-proven hi/lo f16 split (absmax 0.0078).
// Layouts: A row = l&31, k = (l>>5)*8+j ; B col = l&31, k = (l>>5)*8+j ;
// C col = l&31, row = (reg&3) + 8*(reg>>2) + 4*(l>>5)  [guide-verified].

typedef __attribute__((ext_vector_type(8))) _Float16 f16x8;
typedef __attribute__((ext_vector_type(16))) float f32x16;
typedef __attribute__((ext_vector_type(2))) float f32x2;
typedef __attribute__((ext_vector_type(4))) unsigned int u32x4;

#define MFMA32(A,B,C) __builtin_amdgcn_mfma_f32_32x32x16_f16((A),(B),(C),0,0,0)

static __device__ __forceinline__ f32x2 pk_fma(f32x2 a, f32x2 b, f32x2 c) {
    f32x2 d;
    asm("v_pk_fma_f32 %0, %1, %2, %3" : "=v"(d) : "v"(a), "v"(b), "v"(c));
    return d;
}
static __device__ __forceinline__ f32x2 pk_mul(f32x2 a, f32x2 b) {
    f32x2 d;
    asm("v_pk_mul_f32 %0, %1, %2" : "=v"(d) : "v"(a), "v"(b));
    return d;
}
static __device__ __forceinline__ unsigned pkmul16(unsigned a, unsigned b) {
    unsigned d;
    asm("v_pk_mul_f16 %0, %1, %2" : "=v"(d) : "v"(a), "v"(b));
    return d;
}
// v[l] + v[l^32] in every lane (pure VALU)
static __device__ __forceinline__ float hsum32(float v) {
    float a = v, b = v;
    asm("v_permlane32_swap_b32 %0, %1" : "+v"(a), "+v"(b));
    return a + b;
}

__global__ __launch_bounds__(256, 3) void delan_fwd(
    const float* __restrict__ x,
    const float* __restrict__ W1,  const float* __restrict__ b1,
    const float* __restrict__ W1a, const float* __restrict__ b1a,
    const float* __restrict__ W2,  const float* __restrict__ b2,
    const float* __restrict__ W3,  const float* __restrict__ b3,
    const float* __restrict__ W4,  const float* __restrict__ b4,
    float* __restrict__ out, int n_total)
{
    __shared__ _Float16 ahl[2][2][4][64][8];   // [split][H][kblk][lane][j] = 16 KB

    const int tid  = threadIdx.x;
    const int lane = tid & 63;
    const int wid  = tid >> 6;
    const int col  = lane & 31;                 // sample column
    const int g    = lane >> 5;                 // k-subgroup / row-interleave
    const int s    = blockIdx.x * 128 + wid * 32 + col;
    const int sc   = (s < n_total) ? s : (n_total - 1);

    const float2 xa = *(const float2*)(x + 6 * sc);
    const float2 xb = *(const float2*)(x + 6 * sc + 2);
    const float2 xc = *(const float2*)(x + 6 * sc + 4);
    const float x0 = xa.x, x1 = xa.y;
    const float x2 = xb.x, x3 = xb.y;
    const float x4 = xc.x, x5 = xc.y;

    // ---- Build W1a hi/lo A-fragments in LDS (wave wid builds 2 combos) ----
#pragma unroll
    for (int i = 0; i < 2; ++i) {
        const int combo = wid * 2 + i;
        const int H = combo >> 2;
        const int b = combo & 3;
        const int row = 32 * H + col;
        const int ks  = 16 * b + 8 * g;
        const float4 a0 = *(const float4*)(W1a + row * 64 + ks);
        const float4 a1 = *(const float4*)(W1a + row * 64 + ks + 4);
        const float v[8] = {a0.x, a0.y, a0.z, a0.w, a1.x, a1.y, a1.z, a1.w};
        f16x8 hi, lo;
#pragma unroll
        for (int j = 0; j < 8; ++j) {
            const _Float16 h = (_Float16)v[j];
            hi[j] = h;
            lo[j] = (_Float16)((v[j] - (float)h) * 4096.0f);
        }
        *(f16x8*)&ahl[0][H][b][lane][0] = hi;
        *(f16x8*)&ahl[1][H][b][lane][0] = lo;
    }
    __syncthreads();

    // ---- Phase A: B-fragments (this lane: sample=col, k = 16b+8g+j) ----
    const f32x2 q00 = {x0, x0};
    const f32x2 q11 = {x1, x1};
    const f32x2 c4096  = {4096.0f, 4096.0f};
    const f32x2 cm4096 = {-4096.0f, -4096.0f};
    u32x4 Bhh[4], Bhl[4], Bu0[4], Bu1[4];
#pragma unroll
    for (int b = 0; b < 4; ++b) {
        const int kb = 16 * b + 8 * g;
        const float4* wq = (const float4*)(W1 + 2 * kb);   // pairs interleaved
        const float4 bq0 = *(const float4*)(b1 + kb);
        const float4 bq1 = *(const float4*)(b1 + kb + 4);
        const float bv[8] = {bq0.x, bq0.y, bq0.z, bq0.w, bq1.x, bq1.y, bq1.z, bq1.w};
#pragma unroll
        for (int c = 0; c < 4; ++c) {
            const float4 w = wq[c];                 // {w0_e, w1_e, w0_o, w1_o}
            const f32x2 w0p = {w.x, w.z};
            const f32x2 w1p = {w.y, w.w};
            const f32x2 bp  = {bv[2*c], bv[2*c+1]};
            const f32x2 prep = pk_fma(w0p, q00, pk_fma(w1p, q11, bp));
            const bool pos0 = prep.x > 0.0f;
            const bool pos1 = prep.y > 0.0f;
            // u fragments: f16(W1) * f16(dr), dr in {1.0, -0.01}
            const unsigned mlo = pos0 ? 0x00003C00u : 0x0000A11Fu;
            const unsigned mhi = pos1 ? 0x3C000000u : 0xA11F0000u;
            const unsigned drw = mlo | mhi;
            const unsigned p0w = __builtin_bit_cast(unsigned,
                __builtin_amdgcn_cvt_pkrtz(w0p.x, w0p.y));
            const unsigned p1w = __builtin_bit_cast(unsigned,
                __builtin_amdgcn_cvt_pkrtz(w1p.x, w1p.y));
            Bu0[b][c] = pkmul16(p0w, drw);
            Bu1[b][c] = pkmul16(p1w, drw);
            // h1 hi/lo split (residual-corrected, fp32-accurate path)
            f32x2 sp;
            sp.x = pos0 ? 1.0f : 0.01f;
            sp.y = pos1 ? 1.0f : 0.01f;
            const f32x2 h1p = pk_mul(prep, sp);
            const auto hhv = __builtin_amdgcn_cvt_pkrtz(h1p.x, h1p.y);
            Bhh[b][c] = __builtin_bit_cast(unsigned, hhv);
            f32x2 hf;
            hf.x = (float)hhv[0];
            hf.y = (float)hhv[1];
            const f32x2 tt = pk_mul(h1p, c4096);
            const f32x2 rp = pk_fma(hf, cm4096, tt);   // (h1 - hh) * 4096
            Bhl[b][c] = __builtin_bit_cast(unsigned,
                __builtin_amdgcn_cvt_pkrtz(rp.x, rp.y));
        }
    }

    // ---- MFMA over 2 h-halves + fused epilogue ----
    float ag0=0.f, ag1=0.f, al0=0.f, al1=0.f, aoo=0.f;
    float ap00=0.f, ap01=0.f, ap10=0.f, ap11=0.f, ar0=0.f, ar1=0.f;
#pragma unroll
    for (int H = 0; H < 2; ++H) {
        f16x8 Ah[4], Al[4];
#pragma unroll
        for (int b = 0; b < 4; ++b) {
            Ah[b] = *(const f16x8*)&ahl[0][H][b][lane][0];
            Al[b] = *(const f16x8*)&ahl[1][H][b][lane][0];
        }
#define BB(arr, b) __builtin_bit_cast(f16x8, arr[b])
        // Chi initialized with b1a at this lane's C rows
        f32x16 Chi;
#pragma unroll
        for (int rq = 0; rq < 4; ++rq) {
            const float4 bq = *(const float4*)(b1a + 32*H + 8*rq + 4*g);
            Chi[4*rq+0] = bq.x; Chi[4*rq+1] = bq.y;
            Chi[4*rq+2] = bq.z; Chi[4*rq+3] = bq.w;
        }
#pragma unroll
        for (int b = 0; b < 4; ++b) Chi = MFMA32(Ah[b], BB(Bhh,b), Chi);
        f32x16 Clo = {0.f};
#pragma unroll
        for (int b = 0; b < 4; ++b) Clo = MFMA32(Ah[b], BB(Bhl,b), Clo);
#pragma unroll
        for (int b = 0; b < 4; ++b) Clo = MFMA32(Al[b], BB(Bhh,b), Clo);
        float h2v[16];
#pragma unroll
        for (int r = 0; r < 16; ++r) {
            const float ah = fmaf(2.44140625e-4f, Clo[r], Chi[r]);
            h2v[r] = (ah > 0.0f) ? ah : 0.01f * ah;
        }
        f32x16 Cz0 = {0.f};
        f32x16 Cz1 = {0.f};
#pragma unroll
        for (int b = 0; b < 4; ++b) Cz0 = MFMA32(Ah[b], BB(Bu0,b), Cz0);
#pragma unroll
        for (int b = 0; b < 4; ++b) Cz1 = MFMA32(Ah[b], BB(Bu1,b), Cz1);
#undef BB
        // epilogue: rows hb..hb+3 per reg-quad, weights via L1 broadcast
#pragma unroll
        for (int rq = 0; rq < 4; ++rq) {
            const int hb = 32*H + 8*rq + 4*g;
            const float4 w2a = *(const float4*)(W2 + hb);
            const float4 w2b = *(const float4*)(W2 + 64 + hb);
            const float4 w3a = *(const float4*)(W3 + hb);
            const float4 w3b = *(const float4*)(W3 + 64 + hb);
            const float4 w4v = *(const float4*)(W4 + hb);
            const float w2av[4] = {w2a.x, w2a.y, w2a.z, w2a.w};
            const float w2bv[4] = {w2b.x, w2b.y, w2b.z, w2b.w};
            const float w3av[4] = {w3a.x, w3a.y, w3a.z, w3a.w};
            const float w3bv[4] = {w3b.x, w3b.y, w3b.z, w3b.w};
            const float w4vv[4] = {w4v.x, w4v.y, w4v.z, w4v.w};
#pragma unroll
            for (int rr = 0; rr < 4; ++rr) {
                const int r = 4*rq + rr;
                const float h2 = h2v[r];
                const bool pos = h2 > 0.0f;
                ag0 = fmaf(w2av[rr], h2, ag0);   ag1 = fmaf(w2bv[rr], h2, ag1);
                al0 = fmaf(w3av[rr], h2, al0);   al1 = fmaf(w3bv[rr], h2, al1);
                aoo = fmaf(w4vv[rr], h2, aoo);
                const float z0 = Cz0[r], z1 = Cz1[r];
                const float d0 = pos ? z0 : -0.01f * z0;
                const float d1 = pos ? z1 : -0.01f * z1;
                ap00 = fmaf(w3av[rr], d0, ap00); ap01 = fmaf(w3av[rr], d1, ap01);
                ap10 = fmaf(w3bv[rr], d0, ap10); ap11 = fmaf(w3bv[rr], d1, ap11);
                ar0  = fmaf(w4vv[rr], d0, ar0);  ar1  = fmaf(w4vv[rr], d1, ar1);
            }
        }
    }

    // ---- Cross-half reduction: lane l holds 32 h, partner l^32 the rest ----
    const float g0 = hsum32(ag0) + b2[0];
    const float g1 = hsum32(ag1) + b2[1];
    const float l0 = hsum32(al0) + b3[0];
    const float l1 = hsum32(al1) + b3[1];
    const float oo = hsum32(aoo) + b4[0];
    const float p00 = hsum32(ap00), p01 = hsum32(ap01);
    const float p10 = hsum32(ap10), p11 = hsum32(ap11);
    const float r0 = hsum32(ar0),  r1 = hsum32(ar1);

    // ---- Tail: 2x2 algebra (identical to R1/R3; both g-lanes redundantly) ----
    const float ld0 = fmaxf(l0, 0.0f);
    const float ld1 = fmaxf(l1, 0.0f);
    const float dr30 = (l0 > 0.0f) ? 1.0f : 0.0f;
    const float dr31 = (l1 > 0.0f) ? 1.0f : 0.0f;

    const float da00 = dr30 * p00, da01 = dr30 * p01;
    const float da10 = dr31 * p10, da11 = dr31 * p11;

    const float l00 = ld0, l10 = oo, l11 = ld1;

    const float m00 = da00 * x2 + da01 * x3;
    const float m11 = da10 * x2 + da11 * x3;
    const float m10 = r0  * x2 + r1  * x3;

    const float eps = 1e-5f;
    const float Hm00 = fmaf(l00, l00, eps);
    const float Hm01 = l00 * l10;
    const float Hm11 = fmaf(l10, l10, fmaf(l11, l11, eps));

    const float dH00 = 2.0f * l00 * m00;
    const float dH01 = fmaf(l00, m10, l10 * m00);
    const float dH11 = 2.0f * fmaf(l10, m10, l11 * m11);

    const float x22 = x2 * x2, x23 = x2 * x3, x33 = x3 * x3;
    const float quad0 = 2.0f * (da00 * l00 * x22
                      + (fmaf(da00, l10, r0 * l00)) * x23
                      + (fmaf(r0, l10, da10 * l11)) * x33);
    const float quad1 = 2.0f * (da01 * l00 * x22
                      + (fmaf(da01, l10, r1 * l00)) * x23
                      + (fmaf(r1, l10, da11 * l11)) * x33);

    const float c0 = fmaf(dH00, x2, dH01 * x3) - 0.5f * quad0;
    const float c1 = fmaf(dH01, x2, dH11 * x3) - 0.5f * quad1;

    const float tau0 = fmaf(Hm00, x4, Hm01 * x5) + c0 + g0;
    const float tau1 = fmaf(Hm01, x4, Hm11 * x5) + c1 + g1;

    // ---- Stores: g=0 lane writes tau+Hm, g=1 lane writes c+g ----
    if (s < n_total) {
        const long long N = n_total;
        if (g == 0) {
            *((float2*)out + s) = make_float2(tau0, tau1);
            *((float4*)(out + 2 * N) + s) = make_float4(Hm00, Hm01, Hm01, Hm11);
        } else {
            *((float2*)(out + 6 * N) + s) = make_float2(c0, c1);
            *((float2*)(out + 8 * N) + s) = make_float2(g0, g1);
        }
    }
}

extern "C" void kernel_launch(void* const* d_in, const int* in_sizes, int n_in,
                              void* d_out, int out_size, void* d_ws, size_t ws_size,
                              hipStream_t stream) {
    const float* x   = (const float*)d_in[0];
    const float* W1  = (const float*)d_in[1];
    const float* b1  = (const float*)d_in[2];
    const float* W1a = (const float*)d_in[3];
    const float* b1a = (const float*)d_in[4];
    const float* W2  = (const float*)d_in[5];
    const float* b2  = (const float*)d_in[6];
    const float* W3  = (const float*)d_in[7];
    const float* b3  = (const float*)d_in[8];
    const float* W4  = (const float*)d_in[9];
    const float* b4  = (const float*)d_in[10];
    float* out = (float*)d_out;

    const int n_total = in_sizes[0] / 6;
    const int block = 256;
    const int grid = (n_total + 127) / 128;   // 128 samples per block (32/wave)
    delan_fwd<<<grid, block, 0, stream>>>(x, W1, b1, W1a, b1a, W2, b2,
                                          W3, b3, W4, b4, out, n_total);
}